// Round 5
// baseline (147.244 us; speedup 1.0000x reference)
//
#include <hip/hip_runtime.h>
#include <limits.h>

// B=8, Na=Nb=4096, D=64. Top-3 NN by integer quantized coords (>>4, in [0,128)),
// weights 0.5-min(sqrt(d2)/128,0.5), weighted gather of b_feats,
// out = [a_feats | gathered] (B,Na,128) fp32.
//
// Grid algorithm (exact): cell = coord>>3 -> 16^3 cells, ~1 pt/cell.
//  k1: counting-sort b-points by cell into d_ws: table[b][4096]=int2{P,idx},
//      starts[b][4096] (exclusive prefix).
//  k2: per-lane query expands Chebyshev rings r=0,1,... After ring r, any
//      unscanned point has per-axis distance >= 8r+1 (integer coords, cell =
//      [8c,8c+7]) => key >= ((8r+1)^2)<<12. Stop when k2 < that. r<=15 covers
//      the whole grid => unconditionally exact, ties (lowest idx) included via
//      key=(d2<<12)|idx and strict-< stop.
//  Fused gather phase: wave = 64 feature dims, coalesced.
// Fallback: round-4 brute-force kernel if ws_size too small.

#define NA 4096
#define NB 4096
#define FD 64

static __device__ __forceinline__ int med3_i32(int a, int b, int c) {
    int d;
    asm("v_med3_i32 %0, %1, %2, %3" : "=v"(d) : "v"(a), "v"(b), "v"(c));
    return d;
}

static __device__ __forceinline__ int mad_i24(int a, int b, int c) {
    int d;
    asm("v_mad_i32_i24 %0, %1, %2, %3" : "=v"(d) : "v"(a), "v"(b), "v"(c));
    return d;
}

// ---------------- kernel 1: counting sort by cell ----------------
__global__ __launch_bounds__(256) void build_cells(
    const int* __restrict__ b_coords,   // (B, NB, 3)
    int2* __restrict__ table,           // (B, NB) {packed coords, orig idx}
    int*  __restrict__ starts)          // (B, 4096) exclusive prefix
{
    __shared__ int hist[4096];
    __shared__ int wsum[4];
    const int batch = blockIdx.x;
    const int tid   = threadIdx.x;          // 256 threads
    const int lane  = tid & 63, wave = tid >> 6;

    for (int i = tid; i < 4096; i += 256) hist[i] = 0;
    __syncthreads();

    const int* bc = b_coords + (size_t)batch * NB * 3;
    int cellv[16], pk[16];
#pragma unroll
    for (int j = 0; j < 16; ++j) {
        const int i = tid + j * 256;
        const int x = bc[3 * i + 0] >> 4;
        const int y = bc[3 * i + 1] >> 4;
        const int z = bc[3 * i + 2] >> 4;
        pk[j]    = x | (y << 8) | (z << 16);
        cellv[j] = ((z >> 3) << 8) | ((y >> 3) << 4) | (x >> 3);
        atomicAdd(&hist[cellv[j]], 1);
    }
    __syncthreads();

    // exclusive scan of hist[4096]; thread t owns cells [16t, 16t+16)
    const int base = tid << 4;
    int loc[16];
    int sum = 0;
#pragma unroll
    for (int j = 0; j < 16; ++j) { loc[j] = sum; sum += hist[base + j]; }
    int inc = sum;                              // inclusive scan across lanes
    for (int d = 1; d < 64; d <<= 1) {
        const int u = __shfl_up(inc, d, 64);
        if (lane >= d) inc += u;
    }
    if (lane == 63) wsum[wave] = inc;
    __syncthreads();                            // hist reads done; wsum ready
    int woff = 0;
    for (int w = 0; w < 4; ++w) if (w < wave) woff += wsum[w];
    const int excl = woff + inc - sum;          // exclusive prefix of chunk

    int* st = starts + (size_t)batch * 4096;
#pragma unroll
    for (int j = 0; j < 16; ++j) {
        const int s = excl + loc[j];
        hist[base + j] = s;                     // cursor for scatter
        st[base + j]   = s;                     // global starts
    }
    __syncthreads();

    int2* tb = table + (size_t)batch * NB;
#pragma unroll
    for (int j = 0; j < 16; ++j) {
        const int slot = atomicAdd(&hist[cellv[j]], 1);
        int2 e; e.x = pk[j]; e.y = tid + j * 256;   // orig idx
        tb[slot] = e;                           // within-cell order arbitrary:
    }                                           // keys unique, min-3 exact
}

// ---------------- kernel 2: ring query + fused gather ----------------
__global__ __launch_bounds__(128) void query_gather(
    const float* __restrict__ a_feats,
    const float* __restrict__ b_feats,
    const int*   __restrict__ a_coords,
    const int2*  __restrict__ table,
    const int*   __restrict__ starts,
    float* __restrict__ out)
{
    __shared__ int2 s_tab[4096];                // 32 KB
    __shared__ unsigned short s_start[4096];    //  8 KB
    __shared__ int s_keys[128 * 3];             // 1.5 KB

    const int tid   = threadIdx.x;              // 128 threads = 128 queries
    const int batch = blockIdx.x >> 5;          // 32 blocks per batch
    const int qbase = (blockIdx.x & 31) * 128;

    const int2* tb = table  + (size_t)batch * NB;
    const int*  st = starts + (size_t)batch * 4096;
    for (int i = tid; i < 4096; i += 128) {
        s_tab[i]   = tb[i];
        s_start[i] = (unsigned short)st[i];
    }
    __syncthreads();

    const int q  = qbase + tid;
    const int* ac = a_coords + ((size_t)batch * NA + q) * 3;
    const int ax = ac[0] >> 4, ay = ac[1] >> 4, az = ac[2] >> 4;
    const int cx = ax >> 3, cy = ay >> 3, cz = az >> 3;

    int k0 = INT_MAX, k1 = INT_MAX, k2 = INT_MAX;

    for (int r = 0; r < 16; ++r) {
        // ---- scan Chebyshev shell r (skip interior, clamp at [0,16)) ----
        for (int dz = -r; dz <= r; ++dz) {
            const int z = cz + dz;
            if ((unsigned)z > 15u) continue;
            const bool ez = (dz == -r) | (dz == r);
            for (int dy = -r; dy <= r; ++dy) {
                const int y = cy + dy;
                if ((unsigned)y > 15u) continue;
                const bool ey = (dy == -r) | (dy == r);
                const int step = (ez | ey) ? 1 : (2 * r);   // r>0 when chosen
                for (int dx = -r; dx <= r; dx += step) {
                    const int x = cx + dx;
                    if ((unsigned)x > 15u) continue;
                    const int cell = (z << 8) | (y << 4) | x;
                    const int jsb = s_start[cell];
                    const int jeb = (cell == 4095) ? NB : (int)s_start[cell + 1];
                    for (int j = jsb; j < jeb; ++j) {
                        const int2 e = s_tab[j];
                        const int bx = e.x & 255;
                        const int by = (e.x >> 8) & 255;
                        const int bz = e.x >> 16;
                        const int du = ax - bx, dv = ay - by, dw = az - bz;
                        const int d2 = mad_i24(du, du,
                                       mad_i24(dv, dv, __mul24(dw, dw)));
                        const int key = (d2 << 12) | e.y;
                        const int n0 = min(k0, key);
                        const int n1 = med3_i32(k0, k1, key);
                        const int n2 = med3_i32(k1, k2, key);
                        k0 = n0; k1 = n1; k2 = n2;
                    }
                }
            }
        }
        // after covering Chebyshev <= r: unscanned d >= 8r+1 exactly
        const int rr = 8 * r + 1;
        if (k2 < ((rr * rr) << 12)) break;
    }

    s_keys[tid * 3 + 0] = k0;
    s_keys[tid * 3 + 1] = k1;
    s_keys[tid * 3 + 2] = k2;
    __syncthreads();

    // ---- fused gather: wave = 64 feature dims, 2 waves cover 128 queries ----
    const int lane = tid & 63, wave = tid >> 6;
    const float* bfb = b_feats + (size_t)batch * NB * FD;
    for (int qq = wave; qq < 128; qq += 2) {
        const int K0 = s_keys[qq * 3 + 0];
        const int K1 = s_keys[qq * 3 + 1];
        const int K2 = s_keys[qq * 3 + 2];
        const int i0 = K0 & 4095, i1 = K1 & 4095, i2 = K2 & 4095;
        const float w0 = 0.5f - fminf(sqrtf((float)(K0 >> 12)) * (1.0f / 128.0f), 0.5f);
        const float w1 = 0.5f - fminf(sqrtf((float)(K1 >> 12)) * (1.0f / 128.0f), 0.5f);
        const float w2 = 0.5f - fminf(sqrtf((float)(K2 >> 12)) * (1.0f / 128.0f), 0.5f);
        const size_t row = (size_t)batch * NA + (qbase + qq);
        const float g = w0 * bfb[i0 * FD + lane]
                      + w1 * bfb[i1 * FD + lane]
                      + w2 * bfb[i2 * FD + lane];
        out[row * 128 + lane]      = a_feats[row * FD + lane];
        out[row * 128 + 64 + lane] = g;
    }
}

// ---------------- fallback: round-4 brute force (ws too small) ----------------
#define WPB 8
#define MPW 4
#define BLOCK (WPB * 64)
#define APB (WPB * MPW)

__global__ __launch_bounds__(BLOCK, 8) void knn_gather_kernel(
    const float* __restrict__ a_feats, const float* __restrict__ b_feats,
    const int* __restrict__ a_coords, const int* __restrict__ b_coords,
    float* __restrict__ out)
{
    __shared__ int2 s_pg[NB];
    const int batch = blockIdx.y;
    const int tid   = threadIdx.x;
    const int* bc = b_coords + (size_t)batch * NB * 3;
    for (int i = tid; i < NB; i += BLOCK) {
        const int x = bc[3 * i + 0] >> 4;
        const int y = bc[3 * i + 1] >> 4;
        const int z = bc[3 * i + 2] >> 4;
        int2 v;
        v.x = x | (y << 8) | (z << 16);
        v.y = ((__mul24(x, x) + __mul24(y, y) + __mul24(z, z)) << 12) | i;
        s_pg[i] = v;
    }
    __syncthreads();
    const int wave  = tid >> 6;
    const int lane  = tid & 63;
    const int nbase = blockIdx.x * APB + wave * MPW;
    const int* ac = a_coords + ((size_t)batch * NA + nbase) * 3;
    int mx0, my0, mz0, mx1, my1, mz1, mx2, my2, mz2, mx3, my3, mz3;
    int aa0, aa1, aa2, aa3;
    {
        const int x0 = ac[0] >> 4, y0 = ac[1]  >> 4, z0 = ac[2]  >> 4;
        const int x1 = ac[3] >> 4, y1 = ac[4]  >> 4, z1 = ac[5]  >> 4;
        const int x2 = ac[6] >> 4, y2 = ac[7]  >> 4, z2 = ac[8]  >> 4;
        const int x3 = ac[9] >> 4, y3 = ac[10] >> 4, z3 = ac[11] >> 4;
        mx0 = -(x0 << 13); my0 = -(y0 << 13); mz0 = -(z0 << 13);
        mx1 = -(x1 << 13); my1 = -(y1 << 13); mz1 = -(z1 << 13);
        mx2 = -(x2 << 13); my2 = -(y2 << 13); mz2 = -(z2 << 13);
        mx3 = -(x3 << 13); my3 = -(y3 << 13); mz3 = -(z3 << 13);
        aa0 = __mul24(x0, x0) + __mul24(y0, y0) + __mul24(z0, z0);
        aa1 = __mul24(x1, x1) + __mul24(y1, y1) + __mul24(z1, z1);
        aa2 = __mul24(x2, x2) + __mul24(y2, y2) + __mul24(z2, z2);
        aa3 = __mul24(x3, x3) + __mul24(y3, y3) + __mul24(z3, z3);
    }
    int k0_0 = 0x7FFFFFFF, k1_0 = 0x7FFFFFFF, k2_0 = 0x7FFFFFFF;
    int k0_1 = 0x7FFFFFFF, k1_1 = 0x7FFFFFFF, k2_1 = 0x7FFFFFFF;
    int k0_2 = 0x7FFFFFFF, k1_2 = 0x7FFFFFFF, k2_2 = 0x7FFFFFFF;
    int k0_3 = 0x7FFFFFFF, k1_3 = 0x7FFFFFFF, k2_3 = 0x7FFFFFFF;
    const int4* pg4 = (const int4*)s_pg;
#define KNN_PG(PP, GG)                                               \
    {                                                                \
        const int P  = (PP);                                         \
        const int G  = (GG);                                         \
        const int bx = P & 0xFF;                                     \
        const int by = (P >> 8) & 0xFF;                              \
        const int bz = P >> 16;                                      \
        {   const int u = mad_i24(bz, mz0,                           \
                          mad_i24(by, my0, mad_i24(bx, mx0, G)));    \
            const int n0 = min(k0_0, u);                             \
            const int n1 = med3_i32(k0_0, k1_0, u);                  \
            const int n2 = med3_i32(k1_0, k2_0, u);                  \
            k0_0 = n0; k1_0 = n1; k2_0 = n2; }                       \
        {   const int u = mad_i24(bz, mz1,                           \
                          mad_i24(by, my1, mad_i24(bx, mx1, G)));    \
            const int n0 = min(k0_1, u);                             \
            const int n1 = med3_i32(k0_1, k1_1, u);                  \
            const int n2 = med3_i32(k1_1, k2_1, u);                  \
            k0_1 = n0; k1_1 = n1; k2_1 = n2; }                       \
        {   const int u = mad_i24(bz, mz2,                           \
                          mad_i24(by, my2, mad_i24(bx, mx2, G)));    \
            const int n0 = min(k0_2, u);                             \
            const int n1 = med3_i32(k0_2, k1_2, u);                  \
            const int n2 = med3_i32(k1_2, k2_2, u);                  \
            k0_2 = n0; k1_2 = n1; k2_2 = n2; }                       \
        {   const int u = mad_i24(bz, mz3,                           \
                          mad_i24(by, my3, mad_i24(bx, mx3, G)));    \
            const int n0 = min(k0_3, u);                             \
            const int n1 = med3_i32(k0_3, k1_3, u);                  \
            const int n2 = med3_i32(k1_3, k2_3, u);                  \
            k0_3 = n0; k1_3 = n1; k2_3 = n2; }                       \
    }
#pragma unroll 2
    for (int k = 0; k < 16; ++k) {
        const int base = k << 7;
        const int4 X = pg4[base + lane];
        const int4 Y = pg4[base + 64 + lane];
        KNN_PG(X.x, X.y)
        KNN_PG(X.z, X.w)
        KNN_PG(Y.x, Y.y)
        KNN_PG(Y.z, Y.w)
    }
#undef KNN_PG
    const float* bfb = b_feats + (size_t)batch * NB * FD;
    int K0[MPW] = {k0_0, k0_1, k0_2, k0_3};
    int K1[MPW] = {k1_0, k1_1, k1_2, k1_3};
    int K2[MPW] = {k2_0, k2_1, k2_2, k2_3};
    const int AA[MPW] = {aa0, aa1, aa2, aa3};
#pragma unroll
    for (int m = 0; m < MPW; ++m) {
        int a0 = K0[m], a1 = K1[m], a2 = K2[m];
#pragma unroll
        for (int d = 1; d < 64; d <<= 1) {
            const int b0 = __shfl_xor(a0, d, 64);
            const int b1 = __shfl_xor(a1, d, 64);
            const int b2 = __shfl_xor(a2, d, 64);
            const int h0 = max(a0, b0);
            const int l1 = min(a1, b1);
            const int c2 = min(a2, b2);
            a0 = min(a0, b0);
            a1 = min(h0, l1);
            a2 = med3_i32(c2, l1, h0);
        }
        const int i0 = a0 & 4095, i1 = a1 & 4095, i2 = a2 & 4095;
        const float d0 = sqrtf((float)((a0 >> 12) + AA[m])) * (1.0f / 128.0f);
        const float d1 = sqrtf((float)((a1 >> 12) + AA[m])) * (1.0f / 128.0f);
        const float d2 = sqrtf((float)((a2 >> 12) + AA[m])) * (1.0f / 128.0f);
        const float w0 = 0.5f - fminf(d0, 0.5f);
        const float w1 = 0.5f - fminf(d1, 0.5f);
        const float w2 = 0.5f - fminf(d2, 0.5f);
        const size_t row = (size_t)batch * NA + (nbase + m);
        const float g = w0 * bfb[i0 * FD + lane]
                      + w1 * bfb[i1 * FD + lane]
                      + w2 * bfb[i2 * FD + lane];
        out[row * 128 + lane]      = a_feats[row * FD + lane];
        out[row * 128 + 64 + lane] = g;
    }
}

extern "C" void kernel_launch(void* const* d_in, const int* in_sizes, int n_in,
                              void* d_out, int out_size, void* d_ws, size_t ws_size,
                              hipStream_t stream) {
    const float* a_feats  = (const float*)d_in[0];
    const float* b_feats  = (const float*)d_in[1];
    const int*   a_coords = (const int*)d_in[2];
    const int*   b_coords = (const int*)d_in[3];
    float* out = (float*)d_out;

    const int B = in_sizes[0] / (NA * FD);
    const size_t need = (size_t)B * NB * sizeof(int2)      // table
                      + (size_t)B * 4096 * sizeof(int);    // starts

    if (ws_size >= need) {
        int2* table  = (int2*)d_ws;
        int*  starts = (int*)((char*)d_ws + (size_t)B * NB * sizeof(int2));
        build_cells<<<B, 256, 0, stream>>>(b_coords, table, starts);
        query_gather<<<B * 32, 128, 0, stream>>>(a_feats, b_feats, a_coords,
                                                 table, starts, out);
    } else {
        dim3 grid(NA / APB, B);
        knn_gather_kernel<<<grid, BLOCK, 0, stream>>>(a_feats, b_feats,
                                                      a_coords, b_coords, out);
    }
}

// Round 6
// 136.080 us; speedup vs baseline: 1.0820x; 1.0820x over previous
//
#include <hip/hip_runtime.h>
#include <limits.h>

// B=8, Na=Nb=4096, D=64. Top-3 NN by integer quantized coords (>>4, in [0,128)),
// weights 0.5-min(sqrt(d2)/128,0.5), weighted gather of b_feats,
// out = [a_feats | gathered] (B,Na,128) fp32.
//
// Grid algorithm (exact): cell = coord>>3 -> 16^3 cells, ~1 pt/cell.
//  k1: counting-sort b-points by cell (table int2{packedP, idx} + starts).
//  k2: 4 lanes per query. Phase A: uniform predicated scan of the 27-cell
//      neighborhood (7 offsets/lane, <=4 entries batched, rare overflow loop),
//      quad butterfly merge. Certainty: unscanned points after Chebyshev<=1
//      have d >= 9 => key >= 81<<12. Phase C (rare, ~6% of queries): per-lane
//      ring loop r=2..15 gated by wave ballot -- unconditionally exact, ties
//      (lowest idx) via key=(d2<<12)|idx.
//  Fused gather: wave = 64 feature dims, coalesced.
// Fallback: round-4 brute-force kernel if ws too small.

#define NA 4096
#define NB 4096
#define FD 64

static __device__ __forceinline__ int med3_i32(int a, int b, int c) {
    int d;
    asm("v_med3_i32 %0, %1, %2, %3" : "=v"(d) : "v"(a), "v"(b), "v"(c));
    return d;
}

static __device__ __forceinline__ int mad_i24(int a, int b, int c) {
    int d;
    asm("v_mad_i32_i24 %0, %1, %2, %3" : "=v"(d) : "v"(a), "v"(b), "v"(c));
    return d;
}

// ---------------- kernel 1: counting sort by cell ----------------
__global__ __launch_bounds__(256) void build_cells(
    const int* __restrict__ b_coords,   // (B, NB, 3)
    int2* __restrict__ table,           // (B, NB) {packed coords, orig idx}
    int*  __restrict__ starts)          // (B, 4096) exclusive prefix
{
    __shared__ int hist[4096];
    __shared__ int wsum[4];
    const int batch = blockIdx.x;
    const int tid   = threadIdx.x;          // 256 threads
    const int lane  = tid & 63, wave = tid >> 6;

    for (int i = tid; i < 4096; i += 256) hist[i] = 0;
    __syncthreads();

    const int* bc = b_coords + (size_t)batch * NB * 3;
    int cellv[16], pk[16];
#pragma unroll
    for (int j = 0; j < 16; ++j) {
        const int i = tid + j * 256;
        const int x = bc[3 * i + 0] >> 4;
        const int y = bc[3 * i + 1] >> 4;
        const int z = bc[3 * i + 2] >> 4;
        pk[j]    = x | (y << 8) | (z << 16);
        cellv[j] = ((z >> 3) << 8) | ((y >> 3) << 4) | (x >> 3);
        atomicAdd(&hist[cellv[j]], 1);
    }
    __syncthreads();

    // exclusive scan of hist[4096]; thread t owns cells [16t, 16t+16)
    const int base = tid << 4;
    int loc[16];
    int sum = 0;
#pragma unroll
    for (int j = 0; j < 16; ++j) { loc[j] = sum; sum += hist[base + j]; }
    int inc = sum;                              // inclusive scan across lanes
    for (int d = 1; d < 64; d <<= 1) {
        const int u = __shfl_up(inc, d, 64);
        if (lane >= d) inc += u;
    }
    if (lane == 63) wsum[wave] = inc;
    __syncthreads();
    int woff = 0;
    for (int w = 0; w < 4; ++w) if (w < wave) woff += wsum[w];
    const int excl = woff + inc - sum;          // exclusive prefix of chunk

    int* st = starts + (size_t)batch * 4096;
#pragma unroll
    for (int j = 0; j < 16; ++j) {
        const int s = excl + loc[j];
        hist[base + j] = s;                     // cursor for scatter
        st[base + j]   = s;                     // global starts
    }
    __syncthreads();

    int2* tb = table + (size_t)batch * NB;
#pragma unroll
    for (int j = 0; j < 16; ++j) {
        const int slot = atomicAdd(&hist[cellv[j]], 1);
        int2 e; e.x = pk[j]; e.y = tid + j * 256;
        tb[slot] = e;                           // within-cell order arbitrary:
    }                                           // keys unique, min-3 exact
}

// ---------------- kernel 2: quad-per-query + fused gather ----------------
__global__ __launch_bounds__(256) void query_gather(
    const float* __restrict__ a_feats,
    const float* __restrict__ b_feats,
    const int*   __restrict__ a_coords,
    const int2*  __restrict__ table,
    const int*   __restrict__ starts,
    float* __restrict__ out)
{
    __shared__ int s_start[4097];               // 16.4 KB
    __shared__ int s_keys[64 * 3];

    const int tid   = threadIdx.x;              // 256 thr = 64 queries x 4
    const int batch = blockIdx.x >> 6;          // 64 blocks per batch
    const int qbase = (blockIdx.x & 63) * 64;

    const int2* tb = table  + (size_t)batch * NB;
    const int*  st = starts + (size_t)batch * 4096;
    for (int i = tid; i < 4096; i += 256) s_start[i] = st[i];
    if (tid == 0) s_start[4096] = NB;
    __syncthreads();

    const int q  = qbase + (tid >> 2);          // query
    const int qr = tid & 3;                     // quad rank
    const int* ac = a_coords + ((size_t)batch * NA + q) * 3;
    const int ax = ac[0] >> 4, ay = ac[1] >> 4, az = ac[2] >> 4;
    const int cx = ax >> 3, cy = ay >> 3, cz = az >> 3;

    int k0 = INT_MAX, k1 = INT_MAX, k2 = INT_MAX;

#define PROC(EX, EY)                                                  \
    {                                                                 \
        const int bx = (EX) & 255;                                    \
        const int by = ((EX) >> 8) & 255;                             \
        const int bz = (EX) >> 16;                                    \
        const int du = ax - bx, dv = ay - by, dw = az - bz;           \
        const int d2 = mad_i24(du, du, mad_i24(dv, dv,                \
                                               __mul24(dw, dw)));     \
        const int key = (d2 << 12) | (EY);                            \
        const int n0 = min(k0, key);                                  \
        const int n1 = med3_i32(k0, k1, key);                         \
        const int n2 = med3_i32(k1, k2, key);                         \
        k0 = n0; k1 = n1; k2 = n2;                                    \
    }

    // ---- Phase A: 27-cell neighborhood, 7 offsets per lane, uniform ----
    int jsv[7], jev[7];
#pragma unroll
    for (int s = 0; s < 7; ++s) {
        const int o = qr * 7 + s;               // o==27 (qr=3,s=6) is dead
        const int dz = o / 9 - 1;
        const int dy = (o / 3) % 3 - 1;
        const int dx = o % 3 - 1;
        const int x = cx + dx, y = cy + dy, z = cz + dz;
        const bool valid = (o < 27) &
                           ((unsigned)x <= 15u) & ((unsigned)y <= 15u) &
                           ((unsigned)z <= 15u);
        const int cell = (z << 8) | (y << 4) | x;
        const int ci = valid ? cell : 0;
        const int b0 = s_start[ci];
        jsv[s] = b0;
        jev[s] = valid ? s_start[ci + 1] : b0;
    }

#pragma unroll
    for (int s = 0; s < 7; ++s) {
        const int b0 = jsv[s], e0 = jev[s];
        if (b0 < e0) {
            // batched reads: up to 4 entries (P(cell>4 pts) ~= 0.4%).
            // reads may run <=24B past the cell / table end -- stays inside
            // d_ws (next batch's table or the starts array), predicated off.
            const int2 E0 = tb[b0];
            const int2 E1 = tb[b0 + 1];
            const int2 E2 = tb[b0 + 2];
            const int2 E3 = tb[b0 + 3];
            PROC(E0.x, E0.y)
            if (b0 + 1 < e0) PROC(E1.x, E1.y)
            if (b0 + 2 < e0) PROC(E2.x, E2.y)
            if (b0 + 3 < e0) PROC(E3.x, E3.y)
            for (int j = b0 + 4; j < e0; ++j) {   // rare overflow
                const int2 E = tb[j];
                PROC(E.x, E.y)
            }
        }
    }

    // ---- quad butterfly merge (xor 1, 2) of sorted triples ----
#pragma unroll
    for (int d = 1; d <= 2; d <<= 1) {
        const int b0 = __shfl_xor(k0, d, 64);
        const int b1 = __shfl_xor(k1, d, 64);
        const int b2 = __shfl_xor(k2, d, 64);
        const int h0 = max(k0, b0);
        const int l1 = min(k1, b1);
        const int c2 = min(k2, b2);
        k0 = min(k0, b0);
        k1 = min(h0, l1);
        k2 = med3_i32(c2, l1, h0);   // = min(c2, max(l1,h0)), c2 >= min(l1,h0)
    }
    // all 4 lanes of the quad now hold identical sorted top-3

    // ---- Phase C: rare ring expansion r=2..15 (exactness guarantee) ----
    // Entering ring r: Chebyshev <= r-1 fully scanned -> unscanned
    // d >= 8(r-1)+1. All 4 lanes of a needy quad scan redundantly
    // (identical inputs -> triples stay identical; no re-merge needed).
    for (int r = 2; r <= 15; ++r) {
        const int t = 8 * (r - 1) + 1;
        const bool need = (k2 >= ((t * t) << 12));
        if (__ballot(need) == 0ull) break;
        if (need) {
            for (int dz = -r; dz <= r; ++dz) {
                const int z = cz + dz;
                if ((unsigned)z > 15u) continue;
                const bool ezf = (dz == -r) | (dz == r);
                for (int dy = -r; dy <= r; ++dy) {
                    const int y = cy + dy;
                    if ((unsigned)y > 15u) continue;
                    const bool eyf = (dy == -r) | (dy == r);
                    const int step = (ezf | eyf) ? 1 : (2 * r);
                    for (int dx = -r; dx <= r; dx += step) {
                        const int x = cx + dx;
                        if ((unsigned)x > 15u) continue;
                        const int cell = (z << 8) | (y << 4) | x;
                        const int jsb = s_start[cell];
                        const int jeb = s_start[cell + 1];
                        for (int j = jsb; j < jeb; ++j) {
                            const int2 E = tb[j];
                            PROC(E.x, E.y)
                        }
                    }
                }
            }
        }
    }
#undef PROC

    if (qr == 0) {
        const int qs = tid >> 2;
        s_keys[qs * 3 + 0] = k0;
        s_keys[qs * 3 + 1] = k1;
        s_keys[qs * 3 + 2] = k2;
    }
    __syncthreads();

    // ---- fused gather: wave = 64 feature dims, 16 queries per wave ----
    const int lane = tid & 63, wave = tid >> 6;
    const float* bfb = b_feats + (size_t)batch * NB * FD;
#pragma unroll 4
    for (int i = 0; i < 16; ++i) {
        const int qq = wave * 16 + i;
        const int K0 = s_keys[qq * 3 + 0];
        const int K1 = s_keys[qq * 3 + 1];
        const int K2 = s_keys[qq * 3 + 2];
        const int i0 = K0 & 4095, i1 = K1 & 4095, i2 = K2 & 4095;
        const float w0 = 0.5f - fminf(sqrtf((float)(K0 >> 12)) * (1.0f / 128.0f), 0.5f);
        const float w1 = 0.5f - fminf(sqrtf((float)(K1 >> 12)) * (1.0f / 128.0f), 0.5f);
        const float w2 = 0.5f - fminf(sqrtf((float)(K2 >> 12)) * (1.0f / 128.0f), 0.5f);
        const size_t row = (size_t)batch * NA + (qbase + qq);
        const float g = w0 * bfb[i0 * FD + lane]
                      + w1 * bfb[i1 * FD + lane]
                      + w2 * bfb[i2 * FD + lane];
        out[row * 128 + lane]      = a_feats[row * FD + lane];
        out[row * 128 + 64 + lane] = g;
    }
}

// ---------------- fallback: round-4 brute force (ws too small) ----------------
#define WPB 8
#define MPW 4
#define BLOCK (WPB * 64)
#define APB (WPB * MPW)

__global__ __launch_bounds__(BLOCK, 8) void knn_gather_kernel(
    const float* __restrict__ a_feats, const float* __restrict__ b_feats,
    const int* __restrict__ a_coords, const int* __restrict__ b_coords,
    float* __restrict__ out)
{
    __shared__ int2 s_pg[NB];
    const int batch = blockIdx.y;
    const int tid   = threadIdx.x;
    const int* bc = b_coords + (size_t)batch * NB * 3;
    for (int i = tid; i < NB; i += BLOCK) {
        const int x = bc[3 * i + 0] >> 4;
        const int y = bc[3 * i + 1] >> 4;
        const int z = bc[3 * i + 2] >> 4;
        int2 v;
        v.x = x | (y << 8) | (z << 16);
        v.y = ((__mul24(x, x) + __mul24(y, y) + __mul24(z, z)) << 12) | i;
        s_pg[i] = v;
    }
    __syncthreads();
    const int wave  = tid >> 6;
    const int lane  = tid & 63;
    const int nbase = blockIdx.x * APB + wave * MPW;
    const int* ac = a_coords + ((size_t)batch * NA + nbase) * 3;
    int mx0, my0, mz0, mx1, my1, mz1, mx2, my2, mz2, mx3, my3, mz3;
    int aa0, aa1, aa2, aa3;
    {
        const int x0 = ac[0] >> 4, y0 = ac[1]  >> 4, z0 = ac[2]  >> 4;
        const int x1 = ac[3] >> 4, y1 = ac[4]  >> 4, z1 = ac[5]  >> 4;
        const int x2 = ac[6] >> 4, y2 = ac[7]  >> 4, z2 = ac[8]  >> 4;
        const int x3 = ac[9] >> 4, y3 = ac[10] >> 4, z3 = ac[11] >> 4;
        mx0 = -(x0 << 13); my0 = -(y0 << 13); mz0 = -(z0 << 13);
        mx1 = -(x1 << 13); my1 = -(y1 << 13); mz1 = -(z1 << 13);
        mx2 = -(x2 << 13); my2 = -(y2 << 13); mz2 = -(z2 << 13);
        mx3 = -(x3 << 13); my3 = -(y3 << 13); mz3 = -(z3 << 13);
        aa0 = __mul24(x0, x0) + __mul24(y0, y0) + __mul24(z0, z0);
        aa1 = __mul24(x1, x1) + __mul24(y1, y1) + __mul24(z1, z1);
        aa2 = __mul24(x2, x2) + __mul24(y2, y2) + __mul24(z2, z2);
        aa3 = __mul24(x3, x3) + __mul24(y3, y3) + __mul24(z3, z3);
    }
    int k0_0 = 0x7FFFFFFF, k1_0 = 0x7FFFFFFF, k2_0 = 0x7FFFFFFF;
    int k0_1 = 0x7FFFFFFF, k1_1 = 0x7FFFFFFF, k2_1 = 0x7FFFFFFF;
    int k0_2 = 0x7FFFFFFF, k1_2 = 0x7FFFFFFF, k2_2 = 0x7FFFFFFF;
    int k0_3 = 0x7FFFFFFF, k1_3 = 0x7FFFFFFF, k2_3 = 0x7FFFFFFF;
    const int4* pg4 = (const int4*)s_pg;
#define KNN_PG(PP, GG)                                               \
    {                                                                \
        const int P  = (PP);                                         \
        const int G  = (GG);                                         \
        const int bx = P & 0xFF;                                     \
        const int by = (P >> 8) & 0xFF;                              \
        const int bz = P >> 16;                                      \
        {   const int u = mad_i24(bz, mz0,                           \
                          mad_i24(by, my0, mad_i24(bx, mx0, G)));    \
            const int n0 = min(k0_0, u);                             \
            const int n1 = med3_i32(k0_0, k1_0, u);                  \
            const int n2 = med3_i32(k1_0, k2_0, u);                  \
            k0_0 = n0; k1_0 = n1; k2_0 = n2; }                       \
        {   const int u = mad_i24(bz, mz1,                           \
                          mad_i24(by, my1, mad_i24(bx, mx1, G)));    \
            const int n0 = min(k0_1, u);                             \
            const int n1 = med3_i32(k0_1, k1_1, u);                  \
            const int n2 = med3_i32(k1_1, k2_1, u);                  \
            k0_1 = n0; k1_1 = n1; k2_1 = n2; }                       \
        {   const int u = mad_i24(bz, mz2,                           \
                          mad_i24(by, my2, mad_i24(bx, mx2, G)));    \
            const int n0 = min(k0_2, u);                             \
            const int n1 = med3_i32(k0_2, k1_2, u);                  \
            const int n2 = med3_i32(k1_2, k2_2, u);                  \
            k0_2 = n0; k1_2 = n1; k2_2 = n2; }                       \
        {   const int u = mad_i24(bz, mz3,                           \
                          mad_i24(by, my3, mad_i24(bx, mx3, G)));    \
            const int n0 = min(k0_3, u);                             \
            const int n1 = med3_i32(k0_3, k1_3, u);                  \
            const int n2 = med3_i32(k1_3, k2_3, u);                  \
            k0_3 = n0; k1_3 = n1; k2_3 = n2; }                       \
    }
#pragma unroll 2
    for (int k = 0; k < 16; ++k) {
        const int base = k << 7;
        const int4 X = pg4[base + lane];
        const int4 Y = pg4[base + 64 + lane];
        KNN_PG(X.x, X.y)
        KNN_PG(X.z, X.w)
        KNN_PG(Y.x, Y.y)
        KNN_PG(Y.z, Y.w)
    }
#undef KNN_PG
    const float* bfb = b_feats + (size_t)batch * NB * FD;
    int K0[MPW] = {k0_0, k0_1, k0_2, k0_3};
    int K1[MPW] = {k1_0, k1_1, k1_2, k1_3};
    int K2[MPW] = {k2_0, k2_1, k2_2, k2_3};
    const int AA[MPW] = {aa0, aa1, aa2, aa3};
#pragma unroll
    for (int m = 0; m < MPW; ++m) {
        int a0 = K0[m], a1 = K1[m], a2 = K2[m];
#pragma unroll
        for (int d = 1; d < 64; d <<= 1) {
            const int b0 = __shfl_xor(a0, d, 64);
            const int b1 = __shfl_xor(a1, d, 64);
            const int b2 = __shfl_xor(a2, d, 64);
            const int h0 = max(a0, b0);
            const int l1 = min(a1, b1);
            const int c2 = min(a2, b2);
            a0 = min(a0, b0);
            a1 = min(h0, l1);
            a2 = med3_i32(c2, l1, h0);
        }
        const int i0 = a0 & 4095, i1 = a1 & 4095, i2 = a2 & 4095;
        const float d0 = sqrtf((float)((a0 >> 12) + AA[m])) * (1.0f / 128.0f);
        const float d1 = sqrtf((float)((a1 >> 12) + AA[m])) * (1.0f / 128.0f);
        const float d2 = sqrtf((float)((a2 >> 12) + AA[m])) * (1.0f / 128.0f);
        const float w0 = 0.5f - fminf(d0, 0.5f);
        const float w1 = 0.5f - fminf(d1, 0.5f);
        const float w2 = 0.5f - fminf(d2, 0.5f);
        const size_t row = (size_t)batch * NA + (nbase + m);
        const float g = w0 * bfb[i0 * FD + lane]
                      + w1 * bfb[i1 * FD + lane]
                      + w2 * bfb[i2 * FD + lane];
        out[row * 128 + lane]      = a_feats[row * FD + lane];
        out[row * 128 + 64 + lane] = g;
    }
}

extern "C" void kernel_launch(void* const* d_in, const int* in_sizes, int n_in,
                              void* d_out, int out_size, void* d_ws, size_t ws_size,
                              hipStream_t stream) {
    const float* a_feats  = (const float*)d_in[0];
    const float* b_feats  = (const float*)d_in[1];
    const int*   a_coords = (const int*)d_in[2];
    const int*   b_coords = (const int*)d_in[3];
    float* out = (float*)d_out;

    const int B = in_sizes[0] / (NA * FD);
    const size_t need = (size_t)B * NB * sizeof(int2)      // table
                      + (size_t)B * 4096 * sizeof(int);    // starts

    if (ws_size >= need) {
        int2* table  = (int2*)d_ws;
        int*  starts = (int*)((char*)d_ws + (size_t)B * NB * sizeof(int2));
        build_cells<<<B, 256, 0, stream>>>(b_coords, table, starts);
        query_gather<<<B * 64, 256, 0, stream>>>(a_feats, b_feats, a_coords,
                                                 table, starts, out);
    } else {
        dim3 grid(NA / APB, B);
        knn_gather_kernel<<<grid, BLOCK, 0, stream>>>(a_feats, b_feats,
                                                      a_coords, b_coords, out);
    }
}

// Round 8
// 116.458 us; speedup vs baseline: 1.2643x; 1.1685x over previous
//
#include <hip/hip_runtime.h>
#include <limits.h>

// B=8, Na=Nb=4096, D=64. Top-3 NN by integer quantized coords (>>4, in [0,128)),
// weights 0.5-min(sqrt(d2)/128,0.5), weighted gather of b_feats,
// out = [a_feats | gathered] (B,Na,128) fp32.
//
// Grid algorithm (exact): cell = coord>>3 -> 16^3 cells, ~1 pt/cell.
//  k1: counting-sort b-points by cell. Entry = 4 B: ((lx|ly<<3|lz<<6)<<12)|idx
//      (cell-local 3-bit coords + 12-bit original index).
//  k2: 8 lanes per query ("octet"). Table (16 KB) + starts (8 KB ushort) staged
//      in LDS. Phase A: 27-cell neighborhood, 4 cells/lane (disjoint), batched
//      predicated reads; octet butterfly merge (xor 1,2,4). Rings r=2..15:
//      needy octets (ballot-gated) scan shell r counter-strided 8 ways.
//      *** DISJOINTNESS FIX (round 7 bug): the merge network is only valid
//      for disjoint candidate sets, but every lane entered the ring with the
//      same shared base triple -> duplicated elements after re-merge. Now
//      only octet-rank 0 keeps the carried triple; ranks 1-7 reset to
//      INT_MAX before scanning, so the union counts base exactly once. ***
//      Stop when k2 < ((8(r-1)+1)^2)<<12 (Chebyshev<=r-1 covered => unscanned
//      d >= 8(r-1)+1). r to 15 covers the whole grid => unconditionally exact;
//      ties (lowest idx) via key=(d2<<12)|idx, keys unique.
//  Fused gather: wave = 64 feature dims, coalesced.
// Fallback: round-4 brute-force kernel if ws too small.

#define NA 4096
#define NB 4096
#define FD 64
#define QPB 32                 // queries per block
#define LPQ 8                  // lanes per query

static __device__ __forceinline__ int med3_i32(int a, int b, int c) {
    int d;
    asm("v_med3_i32 %0, %1, %2, %3" : "=v"(d) : "v"(a), "v"(b), "v"(c));
    return d;
}

static __device__ __forceinline__ int mad_i24(int a, int b, int c) {
    int d;
    asm("v_mad_i32_i24 %0, %1, %2, %3" : "=v"(d) : "v"(a), "v"(b), "v"(c));
    return d;
}

// ---------------- kernel 1: counting sort by cell (1024 thr) ----------------
__global__ __launch_bounds__(1024) void build_cells(
    const int* __restrict__ b_coords,   // (B, NB, 3)
    int* __restrict__ table,            // (B, NB) packed entries
    int* __restrict__ starts)           // (B, 4096) exclusive prefix
{
    __shared__ int hist[4096];
    __shared__ int wsum[16];
    const int batch = blockIdx.x;
    const int tid   = threadIdx.x;          // 1024 threads
    const int lane  = tid & 63, wave = tid >> 6;

    for (int i = tid; i < 4096; i += 1024) hist[i] = 0;
    __syncthreads();

    const int* bc = b_coords + (size_t)batch * NB * 3;
    int cellv[4], pk[4];
#pragma unroll
    for (int j = 0; j < 4; ++j) {
        const int i = tid + j * 1024;
        const int x = bc[3 * i + 0] >> 4;
        const int y = bc[3 * i + 1] >> 4;
        const int z = bc[3 * i + 2] >> 4;
        cellv[j] = ((z >> 3) << 8) | ((y >> 3) << 4) | (x >> 3);
        pk[j]    = (((x & 7) | ((y & 7) << 3) | ((z & 7) << 6)) << 12) | i;
        atomicAdd(&hist[cellv[j]], 1);
    }
    __syncthreads();

    // exclusive scan; thread t owns cells [4t, 4t+4)
    const int base = tid << 2;
    int loc[4];
    int sum = 0;
#pragma unroll
    for (int j = 0; j < 4; ++j) { loc[j] = sum; sum += hist[base + j]; }
    int inc = sum;
    for (int d = 1; d < 64; d <<= 1) {
        const int u = __shfl_up(inc, d, 64);
        if (lane >= d) inc += u;
    }
    if (lane == 63) wsum[wave] = inc;
    __syncthreads();
    int woff = 0;
#pragma unroll
    for (int w = 0; w < 16; ++w) if (w < wave) woff += wsum[w];
    const int excl = woff + inc - sum;

    int* st = starts + (size_t)batch * 4096;
#pragma unroll
    for (int j = 0; j < 4; ++j) {
        const int s = excl + loc[j];
        hist[base + j] = s;                 // scatter cursor
        st[base + j]   = s;                 // global starts
    }
    __syncthreads();

    int* tb = table + (size_t)batch * NB;
#pragma unroll
    for (int j = 0; j < 4; ++j) {
        const int slot = atomicAdd(&hist[cellv[j]], 1);
        tb[slot] = pk[j];                   // within-cell order arbitrary:
    }                                       // keys unique, min-3 exact
}

// ---------------- kernel 2: octet-per-query + fused gather ----------------
__global__ __launch_bounds__(256) void query_gather(
    const float* __restrict__ a_feats,
    const float* __restrict__ b_feats,
    const int*   __restrict__ a_coords,
    const int*   __restrict__ table,
    const int*   __restrict__ starts,
    float* __restrict__ out)
{
    __shared__ int s_tab[4096 + 4];             // 16 KB (+pad for batched read)
    __shared__ unsigned short s_start[4098];    // 8.2 KB
    __shared__ int s_keys[QPB * 3];

    const int tid   = threadIdx.x;              // 256 thr = 32 queries x 8
    const int batch = blockIdx.x >> 7;          // 128 blocks per batch
    const int qbase = (blockIdx.x & 127) * QPB;

    const int* tb = table  + (size_t)batch * NB;
    const int* st = starts + (size_t)batch * 4096;
    for (int i = tid; i < 4096; i += 256) {
        s_tab[i]   = tb[i];
        s_start[i] = (unsigned short)st[i];
    }
    if (tid == 0) { s_start[4096] = NB; s_start[4097] = NB; }
    __syncthreads();

    const int q  = qbase + (tid >> 3);
    const int qr = tid & 7;                     // octet rank
    const int* ac = a_coords + ((size_t)batch * NA + q) * 3;
    const int ax = ac[0] >> 4, ay = ac[1] >> 4, az = ac[2] >> 4;
    const int cx = ax >> 3, cy = ay >> 3, cz = az >> 3;

    int k0 = INT_MAX, k1 = INT_MAX, k2 = INT_MAX;

#define PROC(E, AXL, AYL, AZL)                                        \
    {                                                                 \
        const int lx = ((E) >> 12) & 7;                               \
        const int ly = ((E) >> 15) & 7;                               \
        const int lz = ((E) >> 18) & 7;                               \
        const int du = (AXL) - lx, dv = (AYL) - ly, dw = (AZL) - lz;  \
        const int d2 = mad_i24(du, du, mad_i24(dv, dv,                \
                                               __mul24(dw, dw)));     \
        const int key = (d2 << 12) | ((E) & 4095);                    \
        const int n0 = min(k0, key);                                  \
        const int n1 = med3_i32(k0, k1, key);                         \
        const int n2 = med3_i32(k1, k2, key);                         \
        k0 = n0; k1 = n1; k2 = n2;                                    \
    }

#define MERGE3(D)                                                     \
    {                                                                 \
        const int b0 = __shfl_xor(k0, (D), 64);                       \
        const int b1 = __shfl_xor(k1, (D), 64);                       \
        const int b2 = __shfl_xor(k2, (D), 64);                       \
        const int h0 = max(k0, b0);                                   \
        const int l1 = min(k1, b1);                                   \
        const int c2 = min(k2, b2);                                   \
        k0 = min(k0, b0);                                             \
        k1 = min(h0, l1);                                             \
        k2 = med3_i32(c2, l1, h0);  /* = min(c2, max(l1,h0)) */       \
    }

    // ---- Phase A: 27-cell neighborhood, 4 cells per lane, uniform.
    //      Lane candidate sets are DISJOINT (each cell -> exactly one lane);
    //      INT_MAX sentinels are harmless padding in the merge. ----
    int js[4], je[4], xl[4], yl[4], zl[4];
#pragma unroll
    for (int s = 0; s < 4; ++s) {
        const int o = qr + (s << 3);            // 0..31; o>=27 dead
        const int dz = o / 9 - 1;
        const int dy = (o / 3) % 3 - 1;
        const int dx = o % 3 - 1;
        const int x = cx + dx, y = cy + dy, z = cz + dz;
        const bool valid = (o < 27) &
                           ((unsigned)x <= 15u) & ((unsigned)y <= 15u) &
                           ((unsigned)z <= 15u);
        const int cell = (z << 8) | (y << 4) | x;
        const int ci = valid ? cell : 0;
        const int b0 = s_start[ci];
        js[s] = b0;
        je[s] = valid ? (int)s_start[ci + 1] : b0;
        xl[s] = ax - (x << 3);
        yl[s] = ay - (y << 3);
        zl[s] = az - (z << 3);
    }

#pragma unroll
    for (int s = 0; s < 4; ++s) {
        const int b0 = js[s], e0 = je[s];
        if (b0 < e0) {
            // up to 4 entries batched (P(cell>4) ~ 0.4%); overread <=16 B
            // lands in s_tab pad, predicated off.
            const int E0 = s_tab[b0];
            const int E1 = s_tab[b0 + 1];
            const int E2 = s_tab[b0 + 2];
            const int E3 = s_tab[b0 + 3];
            PROC(E0, xl[s], yl[s], zl[s])
            if (b0 + 1 < e0) PROC(E1, xl[s], yl[s], zl[s])
            if (b0 + 2 < e0) PROC(E2, xl[s], yl[s], zl[s])
            if (b0 + 3 < e0) PROC(E3, xl[s], yl[s], zl[s])
            for (int j = b0 + 4; j < e0; ++j) {
                const int E = s_tab[j];
                PROC(E, xl[s], yl[s], zl[s])
            }
        }
    }

    // octet butterfly merge: all 8 lanes -> identical sorted top-3
    MERGE3(1) MERGE3(2) MERGE3(4)

    // ---- rings r=2..15: counter-strided shell scan, ballot-gated ----
    // Entering ring r: Chebyshev <= r-1 covered -> unscanned d >= 8(r-1)+1.
    for (int r = 2; r <= 15; ++r) {
        const int t = 8 * (r - 1) + 1;
        const bool need = (k2 >= ((t * t) << 12));   // octet-uniform (shared k2)
        if (__ballot(need) == 0ull) break;
        if (need) {
            // DISJOINTNESS FIX: carried base triple kept on rank 0 only;
            // other ranks reset so the octet union counts it exactly once.
            if (qr != 0) { k0 = INT_MAX; k1 = INT_MAX; k2 = INT_MAX; }
            int c = 0;                      // counts in-bounds shell cells:
            for (int dz = -r; dz <= r; ++dz) {      // uniform within octet
                const int z = cz + dz;
                if ((unsigned)z > 15u) continue;
                const bool ezf = (dz == -r) | (dz == r);
                for (int dy = -r; dy <= r; ++dy) {
                    const int y = cy + dy;
                    if ((unsigned)y > 15u) continue;
                    const bool eyf = (dy == -r) | (dy == r);
                    const int step = (ezf | eyf) ? 1 : (2 * r);
                    for (int dx = -r; dx <= r; dx += step) {
                        const int x = cx + dx;
                        if ((unsigned)x > 15u) continue;
                        if ((c++ & 7) == qr) {
                            const int cell = (z << 8) | (y << 4) | x;
                            const int b0 = s_start[cell];
                            const int e0 = s_start[cell + 1];
                            const int axl = ax - (x << 3);
                            const int ayl = ay - (y << 3);
                            const int azl = az - (z << 3);
                            for (int j = b0; j < e0; ++j) {
                                const int E = s_tab[j];
                                PROC(E, axl, ayl, azl)
                            }
                        }
                    }
                }
            }
            MERGE3(1) MERGE3(2) MERGE3(4)   // disjoint sets -> exact union
        }
    }
#undef PROC
#undef MERGE3

    if (qr == 0) {
        const int qs = tid >> 3;
        s_keys[qs * 3 + 0] = k0;
        s_keys[qs * 3 + 1] = k1;
        s_keys[qs * 3 + 2] = k2;
    }
    __syncthreads();

    // ---- fused gather: wave = 64 feature dims, 8 queries per wave ----
    const int lane = tid & 63, wave = tid >> 6;
    const float* bfb = b_feats + (size_t)batch * NB * FD;
#pragma unroll 2
    for (int i = 0; i < 8; ++i) {
        const int qq = wave * 8 + i;
        const int K0 = s_keys[qq * 3 + 0];
        const int K1 = s_keys[qq * 3 + 1];
        const int K2 = s_keys[qq * 3 + 2];
        const int i0 = K0 & 4095, i1 = K1 & 4095, i2 = K2 & 4095;
        const float w0 = 0.5f - fminf(sqrtf((float)(K0 >> 12)) * (1.0f / 128.0f), 0.5f);
        const float w1 = 0.5f - fminf(sqrtf((float)(K1 >> 12)) * (1.0f / 128.0f), 0.5f);
        const float w2 = 0.5f - fminf(sqrtf((float)(K2 >> 12)) * (1.0f / 128.0f), 0.5f);
        const size_t row = (size_t)batch * NA + (qbase + qq);
        const float g = w0 * bfb[i0 * FD + lane]
                      + w1 * bfb[i1 * FD + lane]
                      + w2 * bfb[i2 * FD + lane];
        out[row * 128 + lane]      = a_feats[row * FD + lane];
        out[row * 128 + 64 + lane] = g;
    }
}

// ---------------- fallback: round-4 brute force (ws too small) ----------------
#define WPB 8
#define MPW 4
#define BLOCK (WPB * 64)
#define APB (WPB * MPW)

__global__ __launch_bounds__(BLOCK, 8) void knn_gather_kernel(
    const float* __restrict__ a_feats, const float* __restrict__ b_feats,
    const int* __restrict__ a_coords, const int* __restrict__ b_coords,
    float* __restrict__ out)
{
    __shared__ int2 s_pg[NB];
    const int batch = blockIdx.y;
    const int tid   = threadIdx.x;
    const int* bc = b_coords + (size_t)batch * NB * 3;
    for (int i = tid; i < NB; i += BLOCK) {
        const int x = bc[3 * i + 0] >> 4;
        const int y = bc[3 * i + 1] >> 4;
        const int z = bc[3 * i + 2] >> 4;
        int2 v;
        v.x = x | (y << 8) | (z << 16);
        v.y = ((__mul24(x, x) + __mul24(y, y) + __mul24(z, z)) << 12) | i;
        s_pg[i] = v;
    }
    __syncthreads();
    const int wave  = tid >> 6;
    const int lane  = tid & 63;
    const int nbase = blockIdx.x * APB + wave * MPW;
    const int* ac = a_coords + ((size_t)batch * NA + nbase) * 3;
    int mx0, my0, mz0, mx1, my1, mz1, mx2, my2, mz2, mx3, my3, mz3;
    int aa0, aa1, aa2, aa3;
    {
        const int x0 = ac[0] >> 4, y0 = ac[1]  >> 4, z0 = ac[2]  >> 4;
        const int x1 = ac[3] >> 4, y1 = ac[4]  >> 4, z1 = ac[5]  >> 4;
        const int x2 = ac[6] >> 4, y2 = ac[7]  >> 4, z2 = ac[8]  >> 4;
        const int x3 = ac[9] >> 4, y3 = ac[10] >> 4, z3 = ac[11] >> 4;
        mx0 = -(x0 << 13); my0 = -(y0 << 13); mz0 = -(z0 << 13);
        mx1 = -(x1 << 13); my1 = -(y1 << 13); mz1 = -(z1 << 13);
        mx2 = -(x2 << 13); my2 = -(y2 << 13); mz2 = -(z2 << 13);
        mx3 = -(x3 << 13); my3 = -(y3 << 13); mz3 = -(z3 << 13);
        aa0 = __mul24(x0, x0) + __mul24(y0, y0) + __mul24(z0, z0);
        aa1 = __mul24(x1, x1) + __mul24(y1, y1) + __mul24(z1, z1);
        aa2 = __mul24(x2, x2) + __mul24(y2, y2) + __mul24(z2, z2);
        aa3 = __mul24(x3, x3) + __mul24(y3, y3) + __mul24(z3, z3);
    }
    int k0_0 = 0x7FFFFFFF, k1_0 = 0x7FFFFFFF, k2_0 = 0x7FFFFFFF;
    int k0_1 = 0x7FFFFFFF, k1_1 = 0x7FFFFFFF, k2_1 = 0x7FFFFFFF;
    int k0_2 = 0x7FFFFFFF, k1_2 = 0x7FFFFFFF, k2_2 = 0x7FFFFFFF;
    int k0_3 = 0x7FFFFFFF, k1_3 = 0x7FFFFFFF, k2_3 = 0x7FFFFFFF;
    const int4* pg4 = (const int4*)s_pg;
#define KNN_PG(PP, GG)                                               \
    {                                                                \
        const int P  = (PP);                                         \
        const int G  = (GG);                                         \
        const int bx = P & 0xFF;                                     \
        const int by = (P >> 8) & 0xFF;                              \
        const int bz = P >> 16;                                      \
        {   const int u = mad_i24(bz, mz0,                           \
                          mad_i24(by, my0, mad_i24(bx, mx0, G)));    \
            const int n0 = min(k0_0, u);                             \
            const int n1 = med3_i32(k0_0, k1_0, u);                  \
            const int n2 = med3_i32(k1_0, k2_0, u);                  \
            k0_0 = n0; k1_0 = n1; k2_0 = n2; }                       \
        {   const int u = mad_i24(bz, mz1,                           \
                          mad_i24(by, my1, mad_i24(bx, mx1, G)));    \
            const int n0 = min(k0_1, u);                             \
            const int n1 = med3_i32(k0_1, k1_1, u);                  \
            const int n2 = med3_i32(k1_1, k2_1, u);                  \
            k0_1 = n0; k1_1 = n1; k2_1 = n2; }                       \
        {   const int u = mad_i24(bz, mz2,                           \
                          mad_i24(by, my2, mad_i24(bx, mx2, G)));    \
            const int n0 = min(k0_2, u);                             \
            const int n1 = med3_i32(k0_2, k1_2, u);                  \
            const int n2 = med3_i32(k1_2, k2_2, u);                  \
            k0_2 = n0; k1_2 = n1; k2_2 = n2; }                       \
        {   const int u = mad_i24(bz, mz3,                           \
                          mad_i24(by, my3, mad_i24(bx, mx3, G)));    \
            const int n0 = min(k0_3, u);                             \
            const int n1 = med3_i32(k0_3, k1_3, u);                  \
            const int n2 = med3_i32(k1_3, k2_3, u);                  \
            k0_3 = n0; k1_3 = n1; k2_3 = n2; }                       \
    }
#pragma unroll 2
    for (int k = 0; k < 16; ++k) {
        const int base = k << 7;
        const int4 X = pg4[base + lane];
        const int4 Y = pg4[base + 64 + lane];
        KNN_PG(X.x, X.y)
        KNN_PG(X.z, X.w)
        KNN_PG(Y.x, Y.y)
        KNN_PG(Y.z, Y.w)
    }
#undef KNN_PG
    const float* bfb = b_feats + (size_t)batch * NB * FD;
    int K0[MPW] = {k0_0, k0_1, k0_2, k0_3};
    int K1[MPW] = {k1_0, k1_1, k1_2, k1_3};
    int K2[MPW] = {k2_0, k2_1, k2_2, k2_3};
    const int AA[MPW] = {aa0, aa1, aa2, aa3};
#pragma unroll
    for (int m = 0; m < MPW; ++m) {
        int a0 = K0[m], a1 = K1[m], a2 = K2[m];
#pragma unroll
        for (int d = 1; d < 64; d <<= 1) {
            const int b0 = __shfl_xor(a0, d, 64);
            const int b1 = __shfl_xor(a1, d, 64);
            const int b2 = __shfl_xor(a2, d, 64);
            const int h0 = max(a0, b0);
            const int l1 = min(a1, b1);
            const int c2 = min(a2, b2);
            a0 = min(a0, b0);
            a1 = min(h0, l1);
            a2 = med3_i32(c2, l1, h0);
        }
        const int i0 = a0 & 4095, i1 = a1 & 4095, i2 = a2 & 4095;
        const float d0 = sqrtf((float)((a0 >> 12) + AA[m])) * (1.0f / 128.0f);
        const float d1 = sqrtf((float)((a1 >> 12) + AA[m])) * (1.0f / 128.0f);
        const float d2 = sqrtf((float)((a2 >> 12) + AA[m])) * (1.0f / 128.0f);
        const float w0 = 0.5f - fminf(d0, 0.5f);
        const float w1 = 0.5f - fminf(d1, 0.5f);
        const float w2 = 0.5f - fminf(d2, 0.5f);
        const size_t row = (size_t)batch * NA + (nbase + m);
        const float g = w0 * bfb[i0 * FD + lane]
                      + w1 * bfb[i1 * FD + lane]
                      + w2 * bfb[i2 * FD + lane];
        out[row * 128 + lane]      = a_feats[row * FD + lane];
        out[row * 128 + 64 + lane] = g;
    }
}

extern "C" void kernel_launch(void* const* d_in, const int* in_sizes, int n_in,
                              void* d_out, int out_size, void* d_ws, size_t ws_size,
                              hipStream_t stream) {
    const float* a_feats  = (const float*)d_in[0];
    const float* b_feats  = (const float*)d_in[1];
    const int*   a_coords = (const int*)d_in[2];
    const int*   b_coords = (const int*)d_in[3];
    float* out = (float*)d_out;

    const int B = in_sizes[0] / (NA * FD);
    const size_t need = (size_t)B * NB * sizeof(int)       // table
                      + (size_t)B * 4096 * sizeof(int);    // starts

    if (ws_size >= need) {
        int* table  = (int*)d_ws;
        int* starts = table + (size_t)B * NB;
        build_cells<<<B, 1024, 0, stream>>>(b_coords, table, starts);
        query_gather<<<B * 128, 256, 0, stream>>>(a_feats, b_feats, a_coords,
                                                  table, starts, out);
    } else {
        dim3 grid(NA / APB, B);
        knn_gather_kernel<<<grid, BLOCK, 0, stream>>>(a_feats, b_feats,
                                                      a_coords, b_coords, out);
    }
}